// Round 5
// baseline (97.699 us; speedup 1.0000x reference)
//
#include <hip/hip_runtime.h>

#define LOG2E 1.4426950408889634f
#define TWO_LOG2E 2.885390081777927f

__device__ __forceinline__ float fast_exp2(float x) { return __builtin_amdgcn_exp2f(x); }
__device__ __forceinline__ float fast_rcp(float x)  { return __builtin_amdgcn_rcpf(x); }

// ---------------------------------------------------------------------------
// K0: zero the attn region (scores are atomically accumulated into it).
// ---------------------------------------------------------------------------
__global__ __launch_bounds__(256) void zero_kernel(float4* __restrict__ p)
{
    p[blockIdx.x * 256 + threadIdx.x] = make_float4(0.f, 0.f, 0.f, 0.f);
}

// ---------------------------------------------------------------------------
// K1: projections. Virtual M=4096 rows: blocks 0..255 -> query*Wq -> qs,
// blocks 256..511 -> value*Wv -> ks. 8 rows per block, 256 threads.
// ---------------------------------------------------------------------------
__global__ __launch_bounds__(256) void proj_kernel(
    const float* __restrict__ query, const float* __restrict__ value,
    const float* __restrict__ Wq, const float* __restrict__ Wv,
    float* __restrict__ qs, float* __restrict__ ks)
{
    __shared__ float in_lds[8 * 256];
    const int t = threadIdx.x;
    const int row0 = blockIdx.x * 8;
    const float* src; const float* W; float* dst;
    if (row0 < 2048) { src = query + (size_t)row0 * 256; W = Wq; dst = qs + (size_t)row0 * 256; }
    else { const int r = row0 - 2048; src = value + (size_t)r * 256; W = Wv; dst = ks + (size_t)r * 256; }

    const float4* s4 = (const float4*)src;
    float4* l4 = (float4*)in_lds;
    l4[t] = s4[t];
    l4[t + 256] = s4[t + 256];
    __syncthreads();

    float acc[8];
#pragma unroll
    for (int r = 0; r < 8; ++r) acc[r] = 0.f;

    for (int d = 0; d < 256; d += 4) {
        const float w0 = W[(d + 0) * 256 + t];
        const float w1 = W[(d + 1) * 256 + t];
        const float w2 = W[(d + 2) * 256 + t];
        const float w3 = W[(d + 3) * 256 + t];
#pragma unroll
        for (int r = 0; r < 8; ++r) {
            const float4 v = *(const float4*)&in_lds[r * 256 + d];
            acc[r] = fmaf(v.x, w0, acc[r]);
            acc[r] = fmaf(v.y, w1, acc[r]);
            acc[r] = fmaf(v.z, w2, acc[r]);
            acc[r] = fmaf(v.w, w3, acc[r]);
        }
    }
#pragma unroll
    for (int r = 0; r < 8; ++r) dst[r * 256 + t] = acc[r];
}

// ---------------------------------------------------------------------------
// K2: shifted additive scores, d-SPLIT: each block computes the partial sum
// over 128 of the 256 d-dims and atomically adds into the (pre-zeroed) attn
// buffer. 2 commutative fp32 adds per location -> deterministic.
//   score*[q,k] = -2 * sum_d scale[d] * sigmoid-term  (row-constant shift
//   vs true score; softmax cancels it).
// Grid = 16(kt) x 16(qt) x 8(b*2+dh) = 2048 blocks x 256 thr = 8192 waves
// (fills all 256 CU x 32 wave slots). Inner body per element:
// add, exp2, add, rcp, fma (3 full-rate + 2 trans). 2x2 tile per thread.
// ---------------------------------------------------------------------------
#define SQ_STRIDE 66
__global__ __launch_bounds__(256) void scores_kernel(
    const float* __restrict__ qs, const float* __restrict__ ks,
    const float* __restrict__ scale, float* __restrict__ attn)
{
    __shared__ float q_lds[32 * SQ_STRIDE];
    __shared__ float k_lds[32 * SQ_STRIDE];
    __shared__ float sc_lds[128];

    const int t = threadIdx.x;
    const int tx = t & 15, ty = t >> 4;
    const int kt = blockIdx.x, qt = blockIdx.y;
    const int b = blockIdx.z >> 1, dh = blockIdx.z & 1;
    const int d0 = dh * 128;
    const float* qbase = qs + (size_t)(b * 512 + qt * 32) * 256 + d0;
    const float* kbase = ks + (size_t)(b * 512 + kt * 32) * 256 + d0;

    if (t < 128) sc_lds[t] = -2.f * scale[d0 + t];

    float a00 = 0.f, a01 = 0.f, a10 = 0.f, a11 = 0.f;

    for (int dc = 0; dc < 128; dc += 64) {
        __syncthreads();
#pragma unroll
        for (int l = 0; l < 2; ++l) {
            const int f = t + 256 * l;
            const int row = f >> 4, c4 = (f & 15) * 4;
            const float4 qv = *(const float4*)&qbase[row * 256 + dc + c4];
            const float4 kv = *(const float4*)&kbase[row * 256 + dc + c4];
            float2 w;
            w.x = qv.x * TWO_LOG2E; w.y = qv.y * TWO_LOG2E;
            *(float2*)&q_lds[row * SQ_STRIDE + c4] = w;
            w.x = qv.z * TWO_LOG2E; w.y = qv.w * TWO_LOG2E;
            *(float2*)&q_lds[row * SQ_STRIDE + c4 + 2] = w;
            w.x = kv.x * TWO_LOG2E; w.y = kv.y * TWO_LOG2E;
            *(float2*)&k_lds[row * SQ_STRIDE + c4] = w;
            w.x = kv.z * TWO_LOG2E; w.y = kv.w * TWO_LOG2E;
            *(float2*)&k_lds[row * SQ_STRIDE + c4 + 2] = w;
        }
        __syncthreads();

#pragma unroll 4
        for (int d = 0; d < 64; d += 2) {
            const float2 s2 = *(const float2*)&sc_lds[dc + d];
            const float2 qa = *(const float2*)&q_lds[(ty * 2 + 0) * SQ_STRIDE + d];
            const float2 qb = *(const float2*)&q_lds[(ty * 2 + 1) * SQ_STRIDE + d];
            const float2 ka = *(const float2*)&k_lds[(tx * 2 + 0) * SQ_STRIDE + d];
            const float2 kb = *(const float2*)&k_lds[(tx * 2 + 1) * SQ_STRIDE + d];

            a00 = fmaf(s2.x, fast_rcp(fast_exp2(qa.x + ka.x) + 1.f), a00);
            a01 = fmaf(s2.x, fast_rcp(fast_exp2(qa.x + kb.x) + 1.f), a01);
            a10 = fmaf(s2.x, fast_rcp(fast_exp2(qb.x + ka.x) + 1.f), a10);
            a11 = fmaf(s2.x, fast_rcp(fast_exp2(qb.x + kb.x) + 1.f), a11);
            a00 = fmaf(s2.y, fast_rcp(fast_exp2(qa.y + ka.y) + 1.f), a00);
            a01 = fmaf(s2.y, fast_rcp(fast_exp2(qa.y + kb.y) + 1.f), a01);
            a10 = fmaf(s2.y, fast_rcp(fast_exp2(qb.y + ka.y) + 1.f), a10);
            a11 = fmaf(s2.y, fast_rcp(fast_exp2(qb.y + kb.y) + 1.f), a11);
        }
    }

    const int qrow = qt * 32 + ty * 2;
    const int kcol = kt * 32 + tx * 2;
    float* p0 = &attn[(size_t)(b * 512 + qrow + 0) * 512 + kcol];
    float* p1 = &attn[(size_t)(b * 512 + qrow + 1) * 512 + kcol];
    unsafeAtomicAdd(p0 + 0, a00);
    unsafeAtomicAdd(p0 + 1, a01);
    unsafeAtomicAdd(p1 + 0, a10);
    unsafeAtomicAdd(p1 + 1, a11);
}

// ---------------------------------------------------------------------------
// K3: softmax in-place over last dim (512). One wave per row.
// ---------------------------------------------------------------------------
__global__ __launch_bounds__(64) void softmax_kernel(float* __restrict__ attn)
{
    const int row = blockIdx.x;
    float4* p4 = (float4*)(attn + (size_t)row * 512);
    const int t = threadIdx.x;
    float4 a = p4[t];
    float4 b = p4[t + 64];

    float m = fmaxf(fmaxf(fmaxf(a.x, a.y), fmaxf(a.z, a.w)),
                    fmaxf(fmaxf(b.x, b.y), fmaxf(b.z, b.w)));
#pragma unroll
    for (int off = 32; off; off >>= 1) m = fmaxf(m, __shfl_xor(m, off));

    a.x = fast_exp2((a.x - m) * LOG2E); a.y = fast_exp2((a.y - m) * LOG2E);
    a.z = fast_exp2((a.z - m) * LOG2E); a.w = fast_exp2((a.w - m) * LOG2E);
    b.x = fast_exp2((b.x - m) * LOG2E); b.y = fast_exp2((b.y - m) * LOG2E);
    b.z = fast_exp2((b.z - m) * LOG2E); b.w = fast_exp2((b.w - m) * LOG2E);

    float sum = ((a.x + a.y) + (a.z + a.w)) + ((b.x + b.y) + (b.z + b.w));
#pragma unroll
    for (int off = 32; off; off >>= 1) sum += __shfl_xor(sum, off);

    const float inv = fast_rcp(sum);
    a.x *= inv; a.y *= inv; a.z *= inv; a.w *= inv;
    b.x *= inv; b.y *= inv; b.z *= inv; b.w *= inv;
    p4[t] = a; p4[t + 64] = b;
}

// ---------------------------------------------------------------------------
// K4: out = attn @ value. Block: 16(q) x 64(i) tile, k chunked by 64.
// 256 threads, each 1(q) x 4(i) accumulator. 512 blocks.
// ---------------------------------------------------------------------------
#define AT_ST 68
#define VT_ST 68
__global__ __launch_bounds__(256) void pv_kernel(
    const float* __restrict__ attn, const float* __restrict__ value,
    float* __restrict__ out)
{
    __shared__ float a_lds[16 * AT_ST];
    __shared__ float v_lds[64 * VT_ST];

    const int t = threadIdx.x;
    const int tx = t & 15, ty = t >> 4;
    const int b = blockIdx.z, qt = blockIdx.y, it = blockIdx.x;
    const int q0 = qt * 16, i0 = it * 64;
    const float* abase = attn + (size_t)(b * 512 + q0) * 512;
    const float* vbase = value + (size_t)(b * 512) * 256 + i0;

    float4 acc = {0, 0, 0, 0};

    for (int kc = 0; kc < 512; kc += 64) {
        __syncthreads();
        {
            const int row = t >> 4, c4 = (t & 15) * 4;
            *(float4*)&a_lds[row * AT_ST + c4] = *(const float4*)&abase[row * 512 + kc + c4];
        }
#pragma unroll
        for (int l = 0; l < 4; ++l) {
            const int f = t + 256 * l;
            const int row = f >> 4, c4 = (f & 15) * 4;
            *(float4*)&v_lds[row * VT_ST + c4] = *(const float4*)&vbase[(size_t)(kc + row) * 256 + c4];
        }
        __syncthreads();

        for (int k = 0; k < 64; ++k) {
            const float a = a_lds[ty * AT_ST + k];
            const float4 v = *(const float4*)&v_lds[k * VT_ST + tx * 4];
            acc.x = fmaf(a, v.x, acc.x);
            acc.y = fmaf(a, v.y, acc.y);
            acc.z = fmaf(a, v.z, acc.z);
            acc.w = fmaf(a, v.w, acc.w);
        }
    }

    *(float4*)&out[(size_t)(b * 512 + q0 + ty) * 256 + i0 + tx * 4] = acc;
}

extern "C" void kernel_launch(void* const* d_in, const int* in_sizes, int n_in,
                              void* d_out, int out_size, void* d_ws, size_t ws_size,
                              hipStream_t stream) {
    const float* query = (const float*)d_in[0];
    const float* value = (const float*)d_in[1];
    const float* Wq    = (const float*)d_in[2];
    const float* Wv    = (const float*)d_in[3];
    const float* scale = (const float*)d_in[4];

    float* out0 = (float*)d_out;                 // [4,512,256]
    float* attn = out0 + 4 * 512 * 256;          // [4,512,512]

    float* qs = (float*)d_ws;                    // [2048,256]
    float* ks = qs + 2048 * 256;                 // [2048,256]

    proj_kernel<<<512, 256, 0, stream>>>(query, value, Wq, Wv, qs, ks);
    zero_kernel<<<1024, 256, 0, stream>>>((float4*)attn);   // 4*512*512 floats
    scores_kernel<<<dim3(16, 16, 8), 256, 0, stream>>>(qs, ks, scale, attn);
    softmax_kernel<<<2048, 64, 0, stream>>>(attn);
    pv_kernel<<<dim3(4, 32, 4), 256, 0, stream>>>(attn, value, out0);
}

// Round 6
// 72.794 us; speedup vs baseline: 1.3421x; 1.3421x over previous
//
#include <hip/hip_runtime.h>

#define LOG2E 1.4426950408889634f
#define TWO_LOG2E 2.885390081777927f

__device__ __forceinline__ float fast_exp2(float x) { return __builtin_amdgcn_exp2f(x); }
__device__ __forceinline__ float fast_rcp(float x)  { return __builtin_amdgcn_rcpf(x); }

// ---------------------------------------------------------------------------
// K1: projections + exp transform. Virtual M=4096 rows: blocks 0..255 ->
// exp2(2*log2e * query*Wq) -> eq, blocks 256..511 -> same for value*Wv -> ek.
// 8 rows per block, 256 threads (one output column each).
// Moving exp2 here costs 1M trans ops total vs 268M in the score loop:
// exp2(q~+k~) = eq*ek, and eq*ek+1 fuses into a single fma in K2.
// ---------------------------------------------------------------------------
__global__ __launch_bounds__(256) void proj_kernel(
    const float* __restrict__ query, const float* __restrict__ value,
    const float* __restrict__ Wq, const float* __restrict__ Wv,
    float* __restrict__ eq, float* __restrict__ ek)
{
    __shared__ float in_lds[8 * 256];
    const int t = threadIdx.x;
    const int row0 = blockIdx.x * 8;
    const float* src; const float* W; float* dst;
    if (row0 < 2048) { src = query + (size_t)row0 * 256; W = Wq; dst = eq + (size_t)row0 * 256; }
    else { const int r = row0 - 2048; src = value + (size_t)r * 256; W = Wv; dst = ek + (size_t)r * 256; }

    const float4* s4 = (const float4*)src;
    float4* l4 = (float4*)in_lds;
    l4[t] = s4[t];
    l4[t + 256] = s4[t + 256];
    __syncthreads();

    float acc[8];
#pragma unroll
    for (int r = 0; r < 8; ++r) acc[r] = 0.f;

    for (int d = 0; d < 256; d += 4) {
        const float w0 = W[(d + 0) * 256 + t];
        const float w1 = W[(d + 1) * 256 + t];
        const float w2 = W[(d + 2) * 256 + t];
        const float w3 = W[(d + 3) * 256 + t];
#pragma unroll
        for (int r = 0; r < 8; ++r) {
            const float4 v = *(const float4*)&in_lds[r * 256 + d];
            acc[r] = fmaf(v.x, w0, acc[r]);
            acc[r] = fmaf(v.y, w1, acc[r]);
            acc[r] = fmaf(v.z, w2, acc[r]);
            acc[r] = fmaf(v.w, w3, acc[r]);
        }
    }
#pragma unroll
    for (int r = 0; r < 8; ++r) dst[r * 256 + t] = fast_exp2(acc[r] * TWO_LOG2E);
}

// ---------------------------------------------------------------------------
// K2: shifted additive scores -> attn region of d_out.
//   score*[q,k] = -2 * sum_d scale[d] / (eq[q,d]*ek[k,d] + 1)
//   = (true score) - sum_d scale[d]: GLOBAL constant shift, softmax cancels.
// Inner body per element: fma(eq,ek,1), rcp, fma(-2s, r, acc)
//   = 2 full-rate + 1 trans = 12 cyc/wave-element.
// Block = 256 thr, 32(q) x 32(k) tile, 2x2 per thread; d chunked by 64.
// Grid 16x16x4 = 1024 blocks = 4096 waves. LDS stride 66: q rows (ty*2+i,
// 4/wave) -> banks {0,4,8,12} free; k rows (tx*2+j) -> 2-way (free, m136).
// ---------------------------------------------------------------------------
#define SQ_STRIDE 66
__global__ __launch_bounds__(256) void scores_kernel(
    const float* __restrict__ eq, const float* __restrict__ ek,
    const float* __restrict__ scale, float* __restrict__ attn)
{
    __shared__ float q_lds[32 * SQ_STRIDE];
    __shared__ float k_lds[32 * SQ_STRIDE];
    __shared__ float sc_lds[256];

    const int t = threadIdx.x;
    const int tx = t & 15, ty = t >> 4;
    const int b = blockIdx.z, qt = blockIdx.y, kt = blockIdx.x;
    const float* qbase = eq + (size_t)(b * 512 + qt * 32) * 256;
    const float* kbase = ek + (size_t)(b * 512 + kt * 32) * 256;

    sc_lds[t] = -2.f * scale[t];

    float a00 = 0.f, a01 = 0.f, a10 = 0.f, a11 = 0.f;

    for (int dc = 0; dc < 256; dc += 64) {
        __syncthreads();
#pragma unroll
        for (int l = 0; l < 2; ++l) {
            const int f = t + 256 * l;
            const int row = f >> 4, c4 = (f & 15) * 4;
            const float4 qv = *(const float4*)&qbase[row * 256 + dc + c4];
            const float4 kv = *(const float4*)&kbase[row * 256 + dc + c4];
            *(float2*)&q_lds[row * SQ_STRIDE + c4]     = make_float2(qv.x, qv.y);
            *(float2*)&q_lds[row * SQ_STRIDE + c4 + 2] = make_float2(qv.z, qv.w);
            *(float2*)&k_lds[row * SQ_STRIDE + c4]     = make_float2(kv.x, kv.y);
            *(float2*)&k_lds[row * SQ_STRIDE + c4 + 2] = make_float2(kv.z, kv.w);
        }
        __syncthreads();

#pragma unroll 4
        for (int d = 0; d < 64; d += 2) {
            const float2 s2 = *(const float2*)&sc_lds[dc + d];
            const float2 qa = *(const float2*)&q_lds[(ty * 2 + 0) * SQ_STRIDE + d];
            const float2 qb = *(const float2*)&q_lds[(ty * 2 + 1) * SQ_STRIDE + d];
            const float2 ka = *(const float2*)&k_lds[(tx * 2 + 0) * SQ_STRIDE + d];
            const float2 kb = *(const float2*)&k_lds[(tx * 2 + 1) * SQ_STRIDE + d];

            a00 = fmaf(s2.x, fast_rcp(fmaf(qa.x, ka.x, 1.f)), a00);
            a01 = fmaf(s2.x, fast_rcp(fmaf(qa.x, kb.x, 1.f)), a01);
            a10 = fmaf(s2.x, fast_rcp(fmaf(qb.x, ka.x, 1.f)), a10);
            a11 = fmaf(s2.x, fast_rcp(fmaf(qb.x, kb.x, 1.f)), a11);
            a00 = fmaf(s2.y, fast_rcp(fmaf(qa.y, ka.y, 1.f)), a00);
            a01 = fmaf(s2.y, fast_rcp(fmaf(qa.y, kb.y, 1.f)), a01);
            a10 = fmaf(s2.y, fast_rcp(fmaf(qb.y, ka.y, 1.f)), a10);
            a11 = fmaf(s2.y, fast_rcp(fmaf(qb.y, kb.y, 1.f)), a11);
        }
    }

    const int qrow = qt * 32 + ty * 2;
    const int kcol = kt * 32 + tx * 2;
    *(float2*)&attn[(size_t)(b * 512 + qrow + 0) * 512 + kcol] = make_float2(a00, a01);
    *(float2*)&attn[(size_t)(b * 512 + qrow + 1) * 512 + kcol] = make_float2(a10, a11);
}

// ---------------------------------------------------------------------------
// K3: softmax in-place over last dim (512). One wave per row.
// ---------------------------------------------------------------------------
__global__ __launch_bounds__(64) void softmax_kernel(float* __restrict__ attn)
{
    const int row = blockIdx.x;
    float4* p4 = (float4*)(attn + (size_t)row * 512);
    const int t = threadIdx.x;
    float4 a = p4[t];
    float4 b = p4[t + 64];

    float m = fmaxf(fmaxf(fmaxf(a.x, a.y), fmaxf(a.z, a.w)),
                    fmaxf(fmaxf(b.x, b.y), fmaxf(b.z, b.w)));
#pragma unroll
    for (int off = 32; off; off >>= 1) m = fmaxf(m, __shfl_xor(m, off));

    a.x = fast_exp2((a.x - m) * LOG2E); a.y = fast_exp2((a.y - m) * LOG2E);
    a.z = fast_exp2((a.z - m) * LOG2E); a.w = fast_exp2((a.w - m) * LOG2E);
    b.x = fast_exp2((b.x - m) * LOG2E); b.y = fast_exp2((b.y - m) * LOG2E);
    b.z = fast_exp2((b.z - m) * LOG2E); b.w = fast_exp2((b.w - m) * LOG2E);

    float sum = ((a.x + a.y) + (a.z + a.w)) + ((b.x + b.y) + (b.z + b.w));
#pragma unroll
    for (int off = 32; off; off >>= 1) sum += __shfl_xor(sum, off);

    const float inv = fast_rcp(sum);
    a.x *= inv; a.y *= inv; a.z *= inv; a.w *= inv;
    b.x *= inv; b.y *= inv; b.z *= inv; b.w *= inv;
    p4[t] = a; p4[t + 64] = b;
}

// ---------------------------------------------------------------------------
// K4: out = attn @ value. Block: 32(q) x 64(i) tile, k chunked by 64.
// 256 threads, each 2(q) x 4(i): per k-step 2 adjacent-stride a-reads
// (ds_read2-friendly) + 1 b128 v-read feed 8 fma -> fma-bound, not LDS-bound.
// Grid (4,16,4) = 256 blocks.
// ---------------------------------------------------------------------------
#define AT_ST 68
#define VT_ST 68
__global__ __launch_bounds__(256) void pv_kernel(
    const float* __restrict__ attn, const float* __restrict__ value,
    float* __restrict__ out)
{
    __shared__ float a_lds[32 * AT_ST];
    __shared__ float v_lds[64 * VT_ST];

    const int t = threadIdx.x;
    const int tx = t & 15, ty = t >> 4;
    const int b = blockIdx.z, qt = blockIdx.y, it = blockIdx.x;
    const int q0 = qt * 32, i0 = it * 64;
    const float* abase = attn + (size_t)(b * 512 + q0) * 512;
    const float* vbase = value + (size_t)(b * 512) * 256 + i0;

    float4 acc0 = {0, 0, 0, 0}, acc1 = {0, 0, 0, 0};

    for (int kc = 0; kc < 512; kc += 64) {
        __syncthreads();
#pragma unroll
        for (int l = 0; l < 2; ++l) {
            const int f = t + 256 * l;
            const int row = f >> 4, c4 = (f & 15) * 4;
            *(float4*)&a_lds[row * AT_ST + c4] = *(const float4*)&abase[row * 512 + kc + c4];
        }
#pragma unroll
        for (int l = 0; l < 4; ++l) {
            const int f = t + 256 * l;
            const int row = f >> 4, c4 = (f & 15) * 4;
            *(float4*)&v_lds[row * VT_ST + c4] = *(const float4*)&vbase[(size_t)(kc + row) * 256 + c4];
        }
        __syncthreads();

        for (int k = 0; k < 64; ++k) {
            const float a0 = a_lds[(ty * 2 + 0) * AT_ST + k];
            const float a1 = a_lds[(ty * 2 + 1) * AT_ST + k];
            const float4 v = *(const float4*)&v_lds[k * VT_ST + tx * 4];
            acc0.x = fmaf(a0, v.x, acc0.x); acc0.y = fmaf(a0, v.y, acc0.y);
            acc0.z = fmaf(a0, v.z, acc0.z); acc0.w = fmaf(a0, v.w, acc0.w);
            acc1.x = fmaf(a1, v.x, acc1.x); acc1.y = fmaf(a1, v.y, acc1.y);
            acc1.z = fmaf(a1, v.z, acc1.z); acc1.w = fmaf(a1, v.w, acc1.w);
        }
    }

    float* obase = out + (size_t)(b * 512 + q0) * 256 + i0;
    *(float4*)&obase[(ty * 2 + 0) * 256 + tx * 4] = acc0;
    *(float4*)&obase[(ty * 2 + 1) * 256 + tx * 4] = acc1;
}

extern "C" void kernel_launch(void* const* d_in, const int* in_sizes, int n_in,
                              void* d_out, int out_size, void* d_ws, size_t ws_size,
                              hipStream_t stream) {
    const float* query = (const float*)d_in[0];
    const float* value = (const float*)d_in[1];
    const float* Wq    = (const float*)d_in[2];
    const float* Wv    = (const float*)d_in[3];
    const float* scale = (const float*)d_in[4];

    float* out0 = (float*)d_out;                 // [4,512,256]
    float* attn = out0 + 4 * 512 * 256;          // [4,512,512] (scores -> softmax in place)

    float* eq = (float*)d_ws;                    // [2048,256] exp2(2*log2e*q)
    float* ek = eq + 2048 * 256;                 // [2048,256] exp2(2*log2e*k)

    proj_kernel<<<512, 256, 0, stream>>>(query, value, Wq, Wv, eq, ek);
    scores_kernel<<<dim3(16, 16, 4), 256, 0, stream>>>(eq, ek, scale, attn);
    softmax_kernel<<<2048, 64, 0, stream>>>(attn);
    pv_kernel<<<dim3(4, 16, 4), 256, 0, stream>>>(attn, value, out0);
}